// Round 4
// baseline (6888.856 us; speedup 1.0000x reference)
//
#include <hip/hip_runtime.h>
#include <math.h>

#define T_ 512
#define B_ 64
#define H_ 512
#define D_ 32
#define G7H (7*H_)          // 3584
#define NBLK 64
#define NTHR 512
#define JPB 8               // hidden channels (j) per block
#define GRPS 8
#define BPG (NBLK/GRPS)     // 8
#define BH (B_*H_)

typedef short bf16x8 __attribute__((ext_vector_type(8)));
typedef float f32x4  __attribute__((ext_vector_type(4)));

__device__ __forceinline__ unsigned short f2bf(float x) {
    unsigned u = __float_as_uint(x);
    unsigned r = (u + 0x7FFFu + ((u >> 16) & 1u)) >> 16;
    return (unsigned short)r;
}
__device__ __forceinline__ float bf2f(unsigned short s) {
    return __uint_as_float(((unsigned)s) << 16);
}

// ---- P2[type][j][gate(8)] = b_gates + embed@W_x  (pad gate 7 = 0) ----
__global__ void precompute_P2(const float* __restrict__ embed,
                              const float* __restrict__ Wg,
                              const float* __restrict__ bg,
                              float* __restrict__ P2) {
    int idx = blockIdx.x * blockDim.x + threadIdx.x;
    if (idx >= 33 * H_ * 8) return;
    int gate = idx & 7;
    int j    = (idx >> 3) & (H_ - 1);
    int type = idx >> 12;
    float acc = 0.f;
    if (gate < 7) {
        acc = bg[gate * H_ + j];
        #pragma unroll
        for (int d = 0; d < D_; ++d)
            acc += embed[type * D_ + d] * Wg[(size_t)d * G7H + gate * H_ + j];
    }
    P2[idx] = acc;
}

// ---- Wt_hi/lo[n][k] = bf16 hi/lo split of W_h^T ----
__global__ void precompute_Wt(const float* __restrict__ Wg,
                              unsigned short* __restrict__ Wth,
                              unsigned short* __restrict__ Wtl) {
    int idx = blockIdx.x * blockDim.x + threadIdx.x;   // n*512 + k
    if (idx >= G7H * H_) return;
    int k = idx & (H_ - 1);
    int n = idx >> 9;
    float w = Wg[(size_t)(D_ + k) * G7H + n];
    unsigned short hi = f2bf(w);
    Wth[idx] = hi;
    Wtl[idx] = f2bf(w - bf2f(hi));
}

// ---- h buffer 0 init (hi/lo split of h0) ----
__global__ void init_h(const float* __restrict__ h0,
                       unsigned short* __restrict__ hh,
                       unsigned short* __restrict__ hl) {
    int idx = blockIdx.x * blockDim.x + threadIdx.x;
    if (idx >= B_ * H_) return;
    float x = h0[idx];
    unsigned short hi = f2bf(x);
    hh[idx] = hi;
    hl[idx] = f2bf(x - bf2f(hi));
}

// ---- two-level grid barrier, monotonic counters, agent-scope relaxed ----
// layout (ints): c1[g] at g*16, c2 at 128, gen at 192
__device__ __forceinline__ void grid_barrier(int* __restrict__ sync, int t, int grp) {
    __syncthreads();   // emits s_waitcnt vmcnt(0): our sc1 stores are at L3
    if (threadIdx.x == 0) {
        int* c1  = sync + grp * 16;
        int* c2  = sync + 128;
        int* gen = sync + 192;
        int old = __hip_atomic_fetch_add(c1, 1, __ATOMIC_RELAXED, __HIP_MEMORY_SCOPE_AGENT);
        bool release = false;
        if (old == (t + 1) * BPG - 1) {
            int o2 = __hip_atomic_fetch_add(c2, 1, __ATOMIC_RELAXED, __HIP_MEMORY_SCOPE_AGENT);
            if (o2 == (t + 1) * GRPS - 1) {
                asm volatile("s_waitcnt vmcnt(0)" ::: "memory");
                __hip_atomic_store(gen, t + 1, __ATOMIC_RELAXED, __HIP_MEMORY_SCOPE_AGENT);
                release = true;
            }
        }
        if (!release) {
            while (__hip_atomic_load(gen, __ATOMIC_RELAXED, __HIP_MEMORY_SCOPE_AGENT) < t + 1)
                __builtin_amdgcn_s_sleep(1);
        }
    }
    __syncthreads();
}

// 16B agent-scope (L2-bypass) load, pipelined
__device__ __forceinline__ bf16x8 load16_sc1(const unsigned short* p) {
    bf16x8 v;
    asm volatile("global_load_dwordx4 %0, %1, off sc1"
                 : "=v"(v) : "v"(p) : "memory");
    return v;
}

// ---------------- persistent recurrent kernel (MFMA) ----------------
__global__ void __launch_bounds__(NTHR, 1)
hawkes_main(const float* __restrict__ seq_dt, const int* __restrict__ seq_types,
            const float* __restrict__ c0, const float* __restrict__ ct0,
            const float* __restrict__ P2,
            const unsigned short* __restrict__ Wth,
            const unsigned short* __restrict__ Wtl,
            unsigned short* __restrict__ hh,   // 2 x (B_*H_) bf16-hi double buffer
            unsigned short* __restrict__ hl,   // 2 x (B_*H_) bf16-lo
            int* __restrict__ sync,
            float* __restrict__ out) {
    __shared__ f32x4 pcl[4][4][64];     // K-half partials: [wm][nt][lane] (16 KB)
    __shared__ float gl[64][68];        // g recurrent part: [b][c_local] (17.4 KB)

    const int tid  = threadIdx.x;
    const int w    = tid >> 6;
    const int lane = tid & 63;
    const int wm   = w & 3;             // m-tile (b-range)
    const int kh   = w >> 2;            // K-half
    const int bid  = blockIdx.x;
    const int grp  = bid & 7;
    const int j0   = grp * 64 + (bid >> 3) * JPB;
    const int m0   = wm * 16;

    // ---- one-time: W B-fragments into registers (persistent across t) ----
    // block cols: c_local = jl*8 + gate (gate 7 = pad), 64 cols = 4 n-tiles
    bf16x8 Bh[4][8], Bl[4][8];
    {
        const bf16x8 zfrag = {0, 0, 0, 0, 0, 0, 0, 0};
        const int krow = (lane >> 4) << 3;
        #pragma unroll
        for (int nt = 0; nt < 4; ++nt) {
            const int c_local = nt * 16 + (lane & 15);
            const int gate = c_local & 7, jl2 = c_local >> 3;
            const bool pad = (gate == 7);
            const size_t nbase = pad ? 0 : (size_t)(gate * H_ + j0 + jl2) * (size_t)H_;
            #pragma unroll
            for (int kt = 0; kt < 8; ++kt) {
                const int k0 = kh * 256 + kt * 32 + krow;
                bf16x8 vh = *(const bf16x8*)(Wth + nbase + k0);
                bf16x8 vl = *(const bf16x8*)(Wtl + nbase + k0);
                Bh[nt][kt] = pad ? zfrag : vh;
                Bl[nt][kt] = pad ? zfrag : vl;
            }
        }
    }

    // ---- persistent cell state: thread owns cell (b=tid>>3, jl=tid&7) ----
    const int eb = tid >> 3, ejl = tid & 7, ej = j0 + ejl;
    float c_s = c0[eb * H_ + ej];
    float ct_s = ct0[eb * H_ + ej];

    const size_t TBH = (size_t)T_ * BH;
    const int arow = m0 + (lane & 15);
    const int kb0  = kh * 256 + ((lane >> 4) << 3);

    for (int t = 0; t < T_; ++t) {
        const unsigned short* ph = hh + (t & 1) * BH + arow * H_ + kb0;
        const unsigned short* pl = hl + (t & 1) * BH + arow * H_ + kb0;

        // A-fragments (h hi/lo): 32 pipelined 16B sc1 loads, one waitcnt
        bf16x8 Ahf[8], Alf[8];
        #pragma unroll
        for (int kt = 0; kt < 8; ++kt) Ahf[kt] = load16_sc1(ph + kt * 32);
        #pragma unroll
        for (int kt = 0; kt < 8; ++kt) Alf[kt] = load16_sc1(pl + kt * 32);
        asm volatile("s_waitcnt vmcnt(0)" ::: "memory");
        __builtin_amdgcn_sched_barrier(0);

        f32x4 acc0 = {0.f,0.f,0.f,0.f}, acc1 = {0.f,0.f,0.f,0.f};
        f32x4 acc2 = {0.f,0.f,0.f,0.f}, acc3 = {0.f,0.f,0.f,0.f};
        #pragma unroll
        for (int kt = 0; kt < 8; ++kt) {
            acc0 = __builtin_amdgcn_mfma_f32_16x16x32_bf16(Ahf[kt], Bh[0][kt], acc0, 0, 0, 0);
            acc1 = __builtin_amdgcn_mfma_f32_16x16x32_bf16(Ahf[kt], Bh[1][kt], acc1, 0, 0, 0);
            acc2 = __builtin_amdgcn_mfma_f32_16x16x32_bf16(Ahf[kt], Bh[2][kt], acc2, 0, 0, 0);
            acc3 = __builtin_amdgcn_mfma_f32_16x16x32_bf16(Ahf[kt], Bh[3][kt], acc3, 0, 0, 0);
            acc0 = __builtin_amdgcn_mfma_f32_16x16x32_bf16(Alf[kt], Bh[0][kt], acc0, 0, 0, 0);
            acc1 = __builtin_amdgcn_mfma_f32_16x16x32_bf16(Alf[kt], Bh[1][kt], acc1, 0, 0, 0);
            acc2 = __builtin_amdgcn_mfma_f32_16x16x32_bf16(Alf[kt], Bh[2][kt], acc2, 0, 0, 0);
            acc3 = __builtin_amdgcn_mfma_f32_16x16x32_bf16(Alf[kt], Bh[3][kt], acc3, 0, 0, 0);
            acc0 = __builtin_amdgcn_mfma_f32_16x16x32_bf16(Ahf[kt], Bl[0][kt], acc0, 0, 0, 0);
            acc1 = __builtin_amdgcn_mfma_f32_16x16x32_bf16(Ahf[kt], Bl[1][kt], acc1, 0, 0, 0);
            acc2 = __builtin_amdgcn_mfma_f32_16x16x32_bf16(Ahf[kt], Bl[2][kt], acc2, 0, 0, 0);
            acc3 = __builtin_amdgcn_mfma_f32_16x16x32_bf16(Ahf[kt], Bl[3][kt], acc3, 0, 0, 0);
        }

        // combine K-halves via LDS, then deposit g into gl[b][c_local]
        if (kh == 1) {
            pcl[wm][0][lane] = acc0; pcl[wm][1][lane] = acc1;
            pcl[wm][2][lane] = acc2; pcl[wm][3][lane] = acc3;
        }
        __syncthreads();
        if (kh == 0) {
            f32x4 s0 = acc0 + pcl[wm][0][lane];
            f32x4 s1 = acc1 + pcl[wm][1][lane];
            f32x4 s2 = acc2 + pcl[wm][2][lane];
            f32x4 s3 = acc3 + pcl[wm][3][lane];
            const int col = lane & 15, rbase = m0 + ((lane >> 4) << 2);
            #pragma unroll
            for (int r = 0; r < 4; ++r) {
                gl[rbase + r][col]      = s0[r];
                gl[rbase + r][16 + col] = s1[r];
                gl[rbase + r][32 + col] = s2[r];
                gl[rbase + r][48 + col] = s3[r];
            }
        }
        __syncthreads();

        // elementwise gate/state update: 512 threads, 1 cell each
        {
            const int b = eb;
            const int type = seq_types[t * B_ + b];
            const float dtv = seq_dt[t * B_ + b];
            const float* pr = P2 + ((size_t)type * H_ + ej) * 8;
            float4 pa = *(const float4*)pr;
            float4 pb = *(const float4*)(pr + 4);
            float4 ga = *(const float4*)&gl[b][ejl * 8];
            float4 gb = *(const float4*)&gl[b][ejl * 8 + 4];
            const float g0 = ga.x + pa.x, g1 = ga.y + pa.y, g2 = ga.z + pa.z, g3 = ga.w + pa.w;
            const float g4 = gb.x + pb.x, g5 = gb.y + pb.y, g6 = gb.z + pb.z;

            const float inpt   = 1.f / (1.f + __expf(-g0));
            const float forget = 1.f / (1.f + __expf(-g1));
            const float output = 1.f / (1.f + __expf(-g2));
            const float in_tar = 1.f / (1.f + __expf(-g3));
            const float fg_tar = 1.f / (1.f + __expf(-g4));
            const float z      = tanhf(g5);
            const float y      = 10.f * g6;
            const float decay  = (fmaxf(y, 0.f) + log1pf(__expf(-fabsf(y)))) * 0.1f;

            const float c_i      = forget * c_s + inpt * z;
            const float ctar_new = fg_tar * ct_s + in_tar * z;
            const float c_t      = ctar_new + (c_i - ctar_new) * __expf(-decay * dtv);
            const float h_t      = output * tanhf(c_t);
            c_s  = c_t;
            ct_s = ctar_new;

            const size_t base = (size_t)t * BH + (size_t)b * H_ + ej;
            out[base]           = h_t;
            out[TBH + base]     = output;
            out[2 * TBH + base] = c_i;
            out[3 * TBH + base] = ctar_new;
            out[4 * TBH + base] = decay;

            // pack hi/lo bf16 of h_t, pairwise u32 agent-scope stores
            unsigned hi16 = f2bf(h_t);
            unsigned lo16 = f2bf(h_t - bf2f((unsigned short)hi16));
            unsigned oth = (unsigned)__shfl_down((int)hi16, 1);
            unsigned otl = (unsigned)__shfl_down((int)lo16, 1);
            if ((ejl & 1) == 0) {
                const int widx = (b * H_ + ej) >> 1;
                unsigned* dh = (unsigned*)(hh + ((t + 1) & 1) * BH) + widx;
                unsigned* dl = (unsigned*)(hl + ((t + 1) & 1) * BH) + widx;
                __hip_atomic_store(dh, hi16 | (oth << 16), __ATOMIC_RELAXED, __HIP_MEMORY_SCOPE_AGENT);
                __hip_atomic_store(dl, lo16 | (otl << 16), __ATOMIC_RELAXED, __HIP_MEMORY_SCOPE_AGENT);
            }
        }
        grid_barrier(sync, t, grp);
    }
}

extern "C" void kernel_launch(void* const* d_in, const int* in_sizes, int n_in,
                              void* d_out, int out_size, void* d_ws, size_t ws_size,
                              hipStream_t stream) {
    const float* seq_dt    = (const float*)d_in[0];
    const int*   seq_types = (const int*)  d_in[1];
    const float* embed     = (const float*)d_in[2];
    const float* W_gates   = (const float*)d_in[3];
    const float* b_gates   = (const float*)d_in[4];
    const float* h0        = (const float*)d_in[5];
    const float* c0        = (const float*)d_in[6];
    const float* ct0       = (const float*)d_in[7];
    float* out = (float*)d_out;

    // workspace: P2 | Wt_hi | Wt_lo | hh(2 buf) | hl(2 buf) | sync
    float* P2 = (float*)d_ws;                                   // 33*512*8 f32
    unsigned short* Wth = (unsigned short*)(P2 + 33 * H_ * 8);  // 3584*512
    unsigned short* Wtl = Wth + (size_t)G7H * H_;
    unsigned short* hh  = Wtl + (size_t)G7H * H_;               // 2*B*H
    unsigned short* hl  = hh + 2 * BH;
    int* sync = (int*)(hl + 2 * BH);

    hipMemsetAsync(sync, 0, 256 * sizeof(int), stream);
    {
        int total = 33 * H_ * 8;
        precompute_P2<<<(total + 255) / 256, 256, 0, stream>>>(embed, W_gates, b_gates, P2);
    }
    {
        int total = G7H * H_;
        precompute_Wt<<<(total + 255) / 256, 256, 0, stream>>>(W_gates, Wth, Wtl);
    }
    {
        int total = BH;
        init_h<<<(total + 255) / 256, 256, 0, stream>>>(h0, hh, hl);
    }
    {
        void* args[] = {(void*)&seq_dt, (void*)&seq_types, (void*)&c0, (void*)&ct0,
                        (void*)&P2, (void*)&Wth, (void*)&Wtl, (void*)&hh, (void*)&hl,
                        (void*)&sync, (void*)&out};
        hipLaunchCooperativeKernel((void*)hawkes_main, dim3(NBLK), dim3(NTHR),
                                   args, 0, stream);
    }
}

// Round 5
// 2706.671 us; speedup vs baseline: 2.5451x; 2.5451x over previous
//
#include <hip/hip_runtime.h>
#include <math.h>

#define T_ 512
#define B_ 64
#define H_ 512
#define D_ 32
#define G7H (7*H_)          // 3584
#define NBLK 128
#define NTHR 512
#define JPB 4               // hidden channels (j) per block -> 32 cols (4 pad)
#define GRPS 8
#define BPG (NBLK/GRPS)     // 16
#define BH (B_*H_)

typedef _Float16 f16x8 __attribute__((ext_vector_type(8)));
typedef float f32x4  __attribute__((ext_vector_type(4)));

// ---- P2[type][j][gate(8)] = b_gates + embed@W_x  (pad gate 7 = 0), exact f32 ----
__global__ void precompute_P2(const float* __restrict__ embed,
                              const float* __restrict__ Wg,
                              const float* __restrict__ bg,
                              float* __restrict__ P2) {
    int idx = blockIdx.x * blockDim.x + threadIdx.x;
    if (idx >= 33 * H_ * 8) return;
    int gate = idx & 7;
    int j    = (idx >> 3) & (H_ - 1);
    int type = idx >> 12;
    float acc = 0.f;
    if (gate < 7) {
        acc = bg[gate * H_ + j];
        #pragma unroll
        for (int d = 0; d < D_; ++d)
            acc += embed[type * D_ + d] * Wg[(size_t)d * G7H + gate * H_ + j];
    }
    P2[idx] = acc;
}

// ---- Wt16[n][k] = fp16(W_h^T) ----
__global__ void precompute_Wt16(const float* __restrict__ Wg,
                                _Float16* __restrict__ Wt) {
    int idx = blockIdx.x * blockDim.x + threadIdx.x;   // n*512 + k
    if (idx >= G7H * H_) return;
    int k = idx & (H_ - 1);
    int n = idx >> 9;
    Wt[idx] = (_Float16)Wg[(size_t)(D_ + k) * G7H + n];
}

// ---- h buffer 0 init (fp16) ----
__global__ void init_h16(const float* __restrict__ h0, _Float16* __restrict__ hf) {
    int idx = blockIdx.x * blockDim.x + threadIdx.x;
    if (idx >= BH) return;
    hf[idx] = (_Float16)h0[idx];
}

// 16B agent-scope (L3-coherent) load, pipelined
__device__ __forceinline__ f16x8 load16_sc1(const _Float16* p) {
    f16x8 v;
    asm volatile("global_load_dwordx4 %0, %1, off sc1"
                 : "=v"(v) : "v"(p) : "memory");
    return v;
}

// ---------------- persistent recurrent kernel (fp16 MFMA) ----------------
__global__ void __launch_bounds__(NTHR, 1)
hawkes_main(const float* __restrict__ seq_dt, const int* __restrict__ seq_types,
            const float* __restrict__ c0, const float* __restrict__ ct0,
            const float* __restrict__ P2,
            const _Float16* __restrict__ Wt,
            _Float16* __restrict__ hf,     // 2 x (B_*H_) fp16 double buffer
            int* __restrict__ sync,
            float* __restrict__ out) {
    __shared__ f32x4 pcl[4][2][64];     // K-half partials: [wm][nt][lane] (8 KB)
    __shared__ float gl[B_][36];        // g recurrent part: [b][c_local] (9 KB)

    const int tid  = threadIdx.x;
    const int w    = tid >> 6;
    const int lane = tid & 63;
    const int wm   = w & 3;             // m-tile (b-range)
    const int kh   = w >> 2;            // K-half
    const int bid  = blockIdx.x;
    const int grp  = bid & 7;
    const int j0   = grp * 64 + (bid >> 3) * JPB;
    const int m0   = wm * 16;

    // ---- one-time: W B-fragments into registers (64 VGPR, persistent) ----
    // block cols: c_local = jl*8 + gate (gate 7 = pad), 32 cols = 2 n-tiles
    f16x8 Bf[2][8];
    {
        const f16x8 zfrag = {0, 0, 0, 0, 0, 0, 0, 0};
        const int krow = (lane >> 4) << 3;
        #pragma unroll
        for (int nt = 0; nt < 2; ++nt) {
            const int c_local = nt * 16 + (lane & 15);
            const int gate = c_local & 7, jl2 = c_local >> 3;
            const bool pad = (gate == 7);
            const size_t nbase = pad ? 0 : (size_t)(gate * H_ + j0 + jl2) * (size_t)H_;
            #pragma unroll
            for (int kt = 0; kt < 8; ++kt) {
                const int k0 = kh * 256 + kt * 32 + krow;
                f16x8 v = *(const f16x8*)(Wt + nbase + k0);
                Bf[nt][kt] = pad ? zfrag : v;
            }
        }
    }

    // ---- persistent cell state: tid<256 owns cell (b=tid>>2, jl=tid&3) ----
    const int eb = tid >> 2, ejl = tid & 3, ej = j0 + ejl;
    float c_s = 0.f, ct_s = 0.f;
    if (tid < 256) {
        c_s  = c0 [eb * H_ + ej];
        ct_s = ct0[eb * H_ + ej];
    }

    const size_t TBH = (size_t)T_ * BH;
    const int arow = m0 + (lane & 15);
    const int kb0  = kh * 256 + ((lane >> 4) << 3);

    for (int t = 0; t < T_; ++t) {
        const _Float16* ph = hf + (t & 1) * BH + arow * H_ + kb0;

        // A-fragments: 8 pipelined 16B sc1 loads, one waitcnt
        f16x8 Af[8];
        #pragma unroll
        for (int kt = 0; kt < 8; ++kt) Af[kt] = load16_sc1(ph + kt * 32);
        asm volatile("s_waitcnt vmcnt(0)" ::: "memory");
        __builtin_amdgcn_sched_barrier(0);

        f32x4 acc0 = {0.f,0.f,0.f,0.f}, acc1 = {0.f,0.f,0.f,0.f};
        #pragma unroll
        for (int kt = 0; kt < 8; ++kt) {
            acc0 = __builtin_amdgcn_mfma_f32_16x16x32_f16(Af[kt], Bf[0][kt], acc0, 0, 0, 0);
            acc1 = __builtin_amdgcn_mfma_f32_16x16x32_f16(Af[kt], Bf[1][kt], acc1, 0, 0, 0);
        }

        // combine K-halves via LDS, deposit g into gl[b][c_local]
        if (kh == 1) { pcl[wm][0][lane] = acc0; pcl[wm][1][lane] = acc1; }
        __syncthreads();
        if (kh == 0) {
            f32x4 s0 = acc0 + pcl[wm][0][lane];
            f32x4 s1 = acc1 + pcl[wm][1][lane];
            const int col = lane & 15, rbase = m0 + ((lane >> 4) << 2);
            #pragma unroll
            for (int r = 0; r < 4; ++r) {
                gl[rbase + r][col]      = s0[r];
                gl[rbase + r][16 + col] = s1[r];
            }
        }
        __syncthreads();

        // elementwise gate/state update: tid<256, 1 cell each
        float h_t = 0.f, outp = 0.f, c_i = 0.f, ctar_new = 0.f, decay = 0.f;
        if (tid < 256) {
            const int b = eb;
            const int type = seq_types[t * B_ + b];
            const float dtv = seq_dt[t * B_ + b];
            const float* pr = P2 + ((size_t)type * H_ + ej) * 8;
            float4 pa = *(const float4*)pr;
            float4 pb = *(const float4*)(pr + 4);
            float4 ga = *(const float4*)&gl[b][ejl * 8];
            float4 gb = *(const float4*)&gl[b][ejl * 8 + 4];
            const float g0 = ga.x + pa.x, g1 = ga.y + pa.y, g2 = ga.z + pa.z, g3 = ga.w + pa.w;
            const float g4 = gb.x + pb.x, g5 = gb.y + pb.y, g6 = gb.z + pb.z;

            const float inpt   = 1.f / (1.f + __expf(-g0));
            const float forget = 1.f / (1.f + __expf(-g1));
            outp               = 1.f / (1.f + __expf(-g2));
            const float in_tar = 1.f / (1.f + __expf(-g3));
            const float fg_tar = 1.f / (1.f + __expf(-g4));
            const float z      = tanhf(g5);
            const float y      = 10.f * g6;
            decay              = (fmaxf(y, 0.f) + log1pf(__expf(-fabsf(y)))) * 0.1f;

            c_i      = forget * c_s + inpt * z;
            ctar_new = fg_tar * ct_s + in_tar * z;
            const float c_t = ctar_new + (c_i - ctar_new) * __expf(-decay * dtv);
            h_t      = outp * tanhf(c_t);
            c_s  = c_t;
            ct_s = ctar_new;

            // recurrent h (fp16), pairwise u32 agent-scope stores
            union { _Float16 f; unsigned short u; } cv; cv.f = (_Float16)h_t;
            unsigned hs = cv.u;
            unsigned oh = (unsigned)__shfl_down((int)hs, 1);
            if ((ejl & 1) == 0) {
                unsigned* dh = (unsigned*)(hf + ((t + 1) & 1) * BH) + ((b * H_ + ej) >> 1);
                __hip_atomic_store(dh, hs | (oh << 16), __ATOMIC_RELAXED, __HIP_MEMORY_SCOPE_AGENT);
            }
        }

        // ---- barrier arrive (h stores drained by syncthreads' vmcnt) ----
        __syncthreads();
        bool release = false;
        if (tid == 0) {
            int* c1  = sync + grp * 16;
            int* c2  = sync + 128;
            int* gen = sync + 192;
            int old = __hip_atomic_fetch_add(c1, 1, __ATOMIC_RELAXED, __HIP_MEMORY_SCOPE_AGENT);
            if (old == (t + 1) * BPG - 1) {
                int o2 = __hip_atomic_fetch_add(c2, 1, __ATOMIC_RELAXED, __HIP_MEMORY_SCOPE_AGENT);
                if (o2 == (t + 1) * GRPS - 1) {
                    asm volatile("s_waitcnt vmcnt(0)" ::: "memory");
                    __hip_atomic_store(gen, t + 1, __ATOMIC_RELAXED, __HIP_MEMORY_SCOPE_AGENT);
                    release = true;
                }
            }
        }

        // ---- output stores overlap with barrier wait ----
        if (tid < 256) {
            const size_t base = (size_t)t * BH + (size_t)eb * H_ + ej;
            out[base]           = h_t;
            out[TBH + base]     = outp;
            out[2 * TBH + base] = c_i;
            out[3 * TBH + base] = ctar_new;
            out[4 * TBH + base] = decay;
        }

        if (tid == 0 && !release) {
            int* gen = sync + 192;
            while (__hip_atomic_load(gen, __ATOMIC_RELAXED, __HIP_MEMORY_SCOPE_AGENT) < t + 1)
                __builtin_amdgcn_s_sleep(1);
        }
        __syncthreads();
    }
}

extern "C" void kernel_launch(void* const* d_in, const int* in_sizes, int n_in,
                              void* d_out, int out_size, void* d_ws, size_t ws_size,
                              hipStream_t stream) {
    const float* seq_dt    = (const float*)d_in[0];
    const int*   seq_types = (const int*)  d_in[1];
    const float* embed     = (const float*)d_in[2];
    const float* W_gates   = (const float*)d_in[3];
    const float* b_gates   = (const float*)d_in[4];
    const float* h0        = (const float*)d_in[5];
    const float* c0        = (const float*)d_in[6];
    const float* ct0       = (const float*)d_in[7];
    float* out = (float*)d_out;

    // workspace: P2 | Wt16 | hf(2 buf) | sync
    float* P2 = (float*)d_ws;                              // 33*512*8 f32
    _Float16* Wt = (_Float16*)(P2 + 33 * H_ * 8);          // 3584*512 fp16
    _Float16* hf = Wt + (size_t)G7H * H_;                  // 2*B*H fp16
    int* sync = (int*)(hf + 2 * BH);

    hipMemsetAsync(sync, 0, 256 * sizeof(int), stream);
    {
        int total = 33 * H_ * 8;
        precompute_P2<<<(total + 255) / 256, 256, 0, stream>>>(embed, W_gates, b_gates, P2);
    }
    {
        int total = G7H * H_;
        precompute_Wt16<<<(total + 255) / 256, 256, 0, stream>>>(W_gates, Wt);
    }
    {
        int total = BH;
        init_h16<<<(total + 255) / 256, 256, 0, stream>>>(h0, hf);
    }
    {
        void* args[] = {(void*)&seq_dt, (void*)&seq_types, (void*)&c0, (void*)&ct0,
                        (void*)&P2, (void*)&Wt, (void*)&hf, (void*)&sync, (void*)&out};
        hipLaunchCooperativeKernel((void*)hawkes_main, dim3(NBLK), dim3(NTHR),
                                   args, 0, stream);
    }
}

// Round 6
// 2038.530 us; speedup vs baseline: 3.3793x; 1.3278x over previous
//
#include <hip/hip_runtime.h>
#include <math.h>

#define T_ 512
#define B_ 64
#define H_ 512
#define D_ 32
#define G7H (7*H_)          // 3584
#define NBLK 128
#define NTHR 512
#define JPB 4               // hidden channels (j) per block -> 32 cols (4 pad)
#define BH (B_*H_)

typedef _Float16 f16x8 __attribute__((ext_vector_type(8)));
typedef float f32x4  __attribute__((ext_vector_type(4)));
typedef int   i32x2  __attribute__((ext_vector_type(2)));

// ---- P2[type][j][gate(8)] = b_gates + embed@W_x  (pad gate 7 = 0), exact f32 ----
__global__ void precompute_P2(const float* __restrict__ embed,
                              const float* __restrict__ Wg,
                              const float* __restrict__ bg,
                              float* __restrict__ P2) {
    int idx = blockIdx.x * blockDim.x + threadIdx.x;
    if (idx >= 33 * H_ * 8) return;
    int gate = idx & 7;
    int j    = (idx >> 3) & (H_ - 1);
    int type = idx >> 12;
    float acc = 0.f;
    if (gate < 7) {
        acc = bg[gate * H_ + j];
        #pragma unroll
        for (int d = 0; d < D_; ++d)
            acc += embed[type * D_ + d] * Wg[(size_t)d * G7H + gate * H_ + j];
    }
    P2[idx] = acc;
}

// ---- Wt16[n][k] = fp16(W_h^T) ----
__global__ void precompute_Wt16(const float* __restrict__ Wg,
                                _Float16* __restrict__ Wt) {
    int idx = blockIdx.x * blockDim.x + threadIdx.x;   // n*512 + k
    if (idx >= G7H * H_) return;
    int k = idx & (H_ - 1);
    int n = idx >> 9;
    Wt[idx] = (_Float16)Wg[(size_t)(D_ + k) * G7H + n];
}

// ---- h buffer 0 init (fp16) ----
__global__ void init_h16(const float* __restrict__ h0, _Float16* __restrict__ hf) {
    int idx = blockIdx.x * blockDim.x + threadIdx.x;
    if (idx >= BH) return;
    hf[idx] = (_Float16)h0[idx];
}

// 16B agent-scope (L3-coherent) load, pipelined
__device__ __forceinline__ f16x8 load16_sc1(const _Float16* p) {
    f16x8 v;
    asm volatile("global_load_dwordx4 %0, %1, off sc1"
                 : "=v"(v) : "v"(p) : "memory");
    return v;
}

__device__ __forceinline__ float fast_rcp(float x) {
    float r;
    asm("v_rcp_f32 %0, %1" : "=v"(r) : "v"(x));
    return r;
}
__device__ __forceinline__ float fast_sigmoid(float x) {
    return fast_rcp(1.f + __expf(-x));
}
__device__ __forceinline__ float fast_tanh(float x) {
    return 1.f - 2.f * fast_rcp(1.f + __expf(2.f * x));
}

// ---------------- persistent recurrent kernel (fp16 MFMA) ----------------
__global__ void __launch_bounds__(NTHR, 1)
hawkes_main(const float* __restrict__ seq_dt, const int* __restrict__ seq_types,
            const float* __restrict__ c0, const float* __restrict__ ct0,
            const float* __restrict__ P2,
            const _Float16* __restrict__ Wt,
            _Float16* __restrict__ hf,     // 2 x (B_*H_) fp16 double buffer
            int* __restrict__ flags,       // NBLK ints, monotonic step counters
            float* __restrict__ out) {
    __shared__ f32x4 pcl[4][2][64];     // K-half partials: [wm][nt][lane] (8 KB)
    __shared__ float gl[B_][36];        // g recurrent part: [b][c_local] (9 KB)

    const int tid  = threadIdx.x;
    const int w    = tid >> 6;
    const int lane = tid & 63;
    const int wm   = w & 3;             // m-tile (b-range)
    const int kh   = w >> 2;            // K-half
    const int bid  = blockIdx.x;
    const int j0   = (bid & 7) * 64 + (bid >> 3) * JPB;   // XCD-grouped j
    const int m0   = wm * 16;

    // ---- one-time: W B-fragments into registers (64 VGPR, persistent) ----
    f16x8 Bf[2][8];
    {
        const f16x8 zfrag = {0, 0, 0, 0, 0, 0, 0, 0};
        const int krow = (lane >> 4) << 3;
        #pragma unroll
        for (int nt = 0; nt < 2; ++nt) {
            const int c_local = nt * 16 + (lane & 15);
            const int gate = c_local & 7, jl2 = c_local >> 3;
            const bool pad = (gate == 7);
            const size_t nbase = pad ? 0 : (size_t)(gate * H_ + j0 + jl2) * (size_t)H_;
            #pragma unroll
            for (int kt = 0; kt < 8; ++kt) {
                const int k0 = kh * 256 + kt * 32 + krow;
                f16x8 v = *(const f16x8*)(Wt + nbase + k0);
                Bf[nt][kt] = pad ? zfrag : v;
            }
        }
    }

    // ---- persistent cell state: tid<256 owns cell (b=tid>>2, jl=tid&3) ----
    const int eb = tid >> 2, ejl = tid & 3, ej = j0 + ejl;
    float c_s = 0.f, ct_s = 0.f;
    if (tid < 256) {
        c_s  = c0 [eb * H_ + ej];
        ct_s = ct0[eb * H_ + ej];
    }

    const size_t TBH = (size_t)T_ * BH;
    const int arow = m0 + (lane & 15);
    const int kb0  = kh * 256 + ((lane >> 4) << 3);

    for (int t = 0; t < T_; ++t) {
        // prefetch per-step scalars + P2 row (L2-resident; hides under MFMA/reduce)
        int   type = 0; float dtv = 0.f;
        float4 pa = {0,0,0,0}, pb = {0,0,0,0};
        if (tid < 256) {
            type = seq_types[t * B_ + eb];
            dtv  = seq_dt  [t * B_ + eb];
            const float* pr = P2 + ((size_t)type * H_ + ej) * 8;
            pa = *(const float4*)pr;
            pb = *(const float4*)(pr + 4);
        }

        const _Float16* ph = hf + (t & 1) * BH + arow * H_ + kb0;

        // A-fragments: 8 pipelined 16B sc1 loads, one waitcnt
        f16x8 Af[8];
        #pragma unroll
        for (int kt = 0; kt < 8; ++kt) Af[kt] = load16_sc1(ph + kt * 32);
        asm volatile("s_waitcnt vmcnt(0)" ::: "memory");
        __builtin_amdgcn_sched_barrier(0);

        f32x4 acc0 = {0.f,0.f,0.f,0.f}, acc1 = {0.f,0.f,0.f,0.f};
        #pragma unroll
        for (int kt = 0; kt < 8; ++kt) {
            acc0 = __builtin_amdgcn_mfma_f32_16x16x32_f16(Af[kt], Bf[0][kt], acc0, 0, 0, 0);
            acc1 = __builtin_amdgcn_mfma_f32_16x16x32_f16(Af[kt], Bf[1][kt], acc1, 0, 0, 0);
        }

        // combine K-halves via LDS, deposit g into gl[b][c_local]
        if (kh == 1) { pcl[wm][0][lane] = acc0; pcl[wm][1][lane] = acc1; }
        __syncthreads();
        if (kh == 0) {
            f32x4 s0 = acc0 + pcl[wm][0][lane];
            f32x4 s1 = acc1 + pcl[wm][1][lane];
            const int col = lane & 15, rbase = m0 + ((lane >> 4) << 2);
            #pragma unroll
            for (int r = 0; r < 4; ++r) {
                gl[rbase + r][col]      = s0[r];
                gl[rbase + r][16 + col] = s1[r];
            }
        }
        __syncthreads();

        // elementwise gate/state update: tid<256, 1 cell each
        float h_t = 0.f, outp = 0.f, c_i = 0.f, ctar_new = 0.f, decay = 0.f;
        if (tid < 256) {
            const int b = eb;
            float4 ga = *(const float4*)&gl[b][ejl * 8];
            float4 gb = *(const float4*)&gl[b][ejl * 8 + 4];
            const float g0 = ga.x + pa.x, g1 = ga.y + pa.y, g2 = ga.z + pa.z, g3 = ga.w + pa.w;
            const float g4 = gb.x + pb.x, g5 = gb.y + pb.y, g6 = gb.z + pb.z;

            const float inpt   = fast_sigmoid(g0);
            const float forget = fast_sigmoid(g1);
            outp               = fast_sigmoid(g2);
            const float in_tar = fast_sigmoid(g3);
            const float fg_tar = fast_sigmoid(g4);
            const float z      = fast_tanh(g5);
            const float y      = 10.f * g6;
            decay              = (fmaxf(y, 0.f) + __logf(1.f + __expf(-fabsf(y)))) * 0.1f;

            c_i      = forget * c_s + inpt * z;
            ctar_new = fg_tar * ct_s + in_tar * z;
            const float c_t = ctar_new + (c_i - ctar_new) * __expf(-decay * dtv);
            h_t      = outp * fast_tanh(c_t);
            c_s  = c_t;
            ct_s = ctar_new;

            // recurrent h (fp16), pairwise u32 agent-scope stores
            union { _Float16 f; unsigned short u; } cv; cv.f = (_Float16)h_t;
            unsigned hs = cv.u;
            unsigned oh = (unsigned)__shfl_down((int)hs, 1);
            if ((ejl & 1) == 0) {
                unsigned* dh = (unsigned*)(hf + ((t + 1) & 1) * BH) + ((eb * H_ + ej) >> 1);
                __hip_atomic_store(dh, hs | (oh << 16), __ATOMIC_RELAXED, __HIP_MEMORY_SCOPE_AGENT);
            }
        }

        // ---- barrier arrive: drain h stores (syncthreads emits vmcnt(0)), set flag ----
        __syncthreads();
        if (tid == 0)
            __hip_atomic_store(flags + bid, t + 1, __ATOMIC_RELAXED, __HIP_MEMORY_SCOPE_AGENT);

        // ---- output stores overlap with barrier wait ----
        if (tid < 256) {
            const size_t base = (size_t)t * BH + (size_t)eb * H_ + ej;
            out[base]           = h_t;
            out[TBH + base]     = outp;
            out[2 * TBH + base] = c_i;
            out[3 * TBH + base] = ctar_new;
            out[4 * TBH + base] = decay;
        }

        // ---- wave-parallel poll: lane i watches flags 2i, 2i+1 ----
        if (w == 0) {
            const int* fp = flags + 2 * lane;
            int ok;
            do {
                i32x2 vv;
                asm volatile("global_load_dwordx2 %0, %1, off sc1\n\t"
                             "s_waitcnt vmcnt(0)"
                             : "=&v"(vv) : "v"(fp) : "memory");
                ok = (vv.x >= t + 1) && (vv.y >= t + 1);
            } while (!__all(ok));
        }
        __syncthreads();
    }
}

extern "C" void kernel_launch(void* const* d_in, const int* in_sizes, int n_in,
                              void* d_out, int out_size, void* d_ws, size_t ws_size,
                              hipStream_t stream) {
    const float* seq_dt    = (const float*)d_in[0];
    const int*   seq_types = (const int*)  d_in[1];
    const float* embed     = (const float*)d_in[2];
    const float* W_gates   = (const float*)d_in[3];
    const float* b_gates   = (const float*)d_in[4];
    const float* h0        = (const float*)d_in[5];
    const float* c0        = (const float*)d_in[6];
    const float* ct0       = (const float*)d_in[7];
    float* out = (float*)d_out;

    // workspace: P2 | Wt16 | hf(2 buf) | flags
    float* P2 = (float*)d_ws;                              // 33*512*8 f32
    _Float16* Wt = (_Float16*)(P2 + 33 * H_ * 8);          // 3584*512 fp16
    _Float16* hf = Wt + (size_t)G7H * H_;                  // 2*B*H fp16
    int* flags = (int*)(hf + 2 * BH);

    hipMemsetAsync(flags, 0, NBLK * sizeof(int), stream);
    {
        int total = 33 * H_ * 8;
        precompute_P2<<<(total + 255) / 256, 256, 0, stream>>>(embed, W_gates, b_gates, P2);
    }
    {
        int total = G7H * H_;
        precompute_Wt16<<<(total + 255) / 256, 256, 0, stream>>>(W_gates, Wt);
    }
    {
        int total = BH;
        init_h16<<<(total + 255) / 256, 256, 0, stream>>>(h0, hf);
    }
    {
        void* args[] = {(void*)&seq_dt, (void*)&seq_types, (void*)&c0, (void*)&ct0,
                        (void*)&P2, (void*)&Wt, (void*)&hf, (void*)&flags, (void*)&out};
        hipLaunchCooperativeKernel((void*)hawkes_main, dim3(NBLK), dim3(NTHR),
                                   args, 0, stream);
    }
}